// Round 13
// baseline (509.210 us; speedup 1.0000x reference)
//
#include <hip/hip_runtime.h>

// Problem constants
#define B_    2
#define T_    2048
#define HID_  2048
#define NH_   32
#define NKV_  8
#define HD_   64
#define STEPS_ 2
#define SCALE_ 0.125f
// SCALE * log2(e): scores kept in exp2 domain throughout (folded into q at RoPE)
#define CSC_  0.18033688011112042f

typedef float   f32x4  __attribute__((ext_vector_type(4)));
typedef __bf16  bf16x8 __attribute__((ext_vector_type(8)));
typedef unsigned short u16x8 __attribute__((ext_vector_type(8)));

__device__ __forceinline__ unsigned short f2bf(float f) {
  unsigned int u = __builtin_bit_cast(unsigned int, f);
  u = (u + 0x7fffu + ((u >> 16) & 1u)) >> 16;
  return (unsigned short)u;
}
__device__ __forceinline__ float bf2f(unsigned short h) {
  unsigned int u = ((unsigned int)h) << 16;
  return __builtin_bit_cast(float, u);
}
__device__ __forceinline__ bf16x8 frag_ld(const unsigned short* p) {
  u16x8 v = *(const u16x8*)p;
  return __builtin_bit_cast(bf16x8, v);
}
__device__ __forceinline__ f32x4 mfma16(bf16x8 a, bf16x8 b, f32x4 c) {
  return __builtin_amdgcn_mfma_f32_16x16x32_bf16(a, b, c, 0, 0, 0);
}
__device__ __forceinline__ void async_cp16(const void* g, void* l) {
  __builtin_amdgcn_global_load_lds(
      (const __attribute__((address_space(1))) void*)g,
      (__attribute__((address_space(3))) void*)l, 16, 0, 0);
}
// HW packed f32->bf16 (RNE), no builtin on gfx950 -> inline asm (guide T12)
__device__ __forceinline__ unsigned int cvtpk_bf16(float lo, float hi) {
  unsigned int r;
  asm("v_cvt_pk_bf16_f32 %0, %1, %2" : "=v"(r) : "v"(lo), "v"(hi));
  return r;
}

// ---------------------------------------------------------------------------
// MERGED preprocessing: one dispatch, block-range switch.
//  [0, 16384)          convert X fp32 -> Xb bf16            (4 f32/thread)
//  [16384, 24576)      convert prev_k[0] -> k0b bf16
//  [24576, 26112)      transpose Wq/Wk/Wv -> WqkvT (128-wide k-tiles)
//  [26112, 26624)      transpose Wo -> WoT
//  [26624, 27648)      transpose prev_v[0] slabs -> v0t
__global__ __launch_bounds__(256) void preproc(const float* __restrict__ X,
                                               const float* __restrict__ prevk,
                                               const float* __restrict__ prevv,
                                               const float* __restrict__ Wq,
                                               const float* __restrict__ Wk,
                                               const float* __restrict__ Wv,
                                               const float* __restrict__ Wo,
                                               unsigned short* __restrict__ Xb,
                                               unsigned short* __restrict__ k0b,
                                               unsigned short* __restrict__ WqkvT,
                                               unsigned short* __restrict__ WoT,
                                               unsigned short* __restrict__ v0t) {
  __shared__ float tile[128][65];
  const int tid = threadIdx.x;
  int blk = blockIdx.x;

  if (blk < 16384) {                      // convert X (4194304 float4 exactly)
    int idx = blk * 256 + tid;
    float4 v = ((const float4*)X)[idx];
    ushort4 o;
    o.x = f2bf(v.x); o.y = f2bf(v.y); o.z = f2bf(v.z); o.w = f2bf(v.w);
    ((ushort4*)Xb)[idx] = o;
    return;
  }
  blk -= 16384;
  if (blk < 8192) {                       // convert prev_k[0] (2097152 float4)
    int idx = blk * 256 + tid;
    float4 v = ((const float4*)prevk)[idx];
    ushort4 o;
    o.x = f2bf(v.x); o.y = f2bf(v.y); o.z = f2bf(v.z); o.w = f2bf(v.w);
    ((ushort4*)k0b)[idx] = o;
    return;
  }
  blk -= 8192;

  const float* in;
  unsigned short* out;
  int N, ldo, k0, n0;
  if (blk < 1536) {                       // Wq/Wk/Wv -> WqkvT [3072][4096]
    int nt = blk % 48, kt = blk / 48;     // kt 0..31
    k0 = kt * 128;
    ldo = 4096;
    if (nt < 32)      { in = Wq; N = 2048; out = WqkvT;                         n0 = nt * 64; }
    else if (nt < 40) { in = Wk; N = 512;  out = WqkvT + (size_t)2048 * 4096;   n0 = (nt - 32) * 64; }
    else              { in = Wv; N = 512;  out = WqkvT + (size_t)2560 * 4096;   n0 = (nt - 40) * 64; }
  } else if (blk < 2048) {                // Wo (2048x2048) -> WoT
    int q = blk - 1536;
    int nt = q % 32, kt = q / 32;         // kt 0..15
    in = Wo; out = WoT; N = 2048; ldo = 2048;
    k0 = kt * 128; n0 = nt * 64;
  } else {                                // prev_v[0] slabs -> v0t [bh][64][T]
    int q = blk - 2048;
    int st = q % 16, bh = q / 16;         // st 0..15, bh 0..63
    in = prevv + (size_t)bh * T_ * HD_;
    out = v0t + (size_t)bh * HD_ * T_;
    N = 64; ldo = T_;
    k0 = st * 128; n0 = 0;
  }

  const int c = tid & 63, w = tid >> 6;
#pragma unroll
  for (int i = 0; i < 32; i++) {
    int r = w * 32 + i;
    tile[r][c] = in[(size_t)(k0 + r) * N + n0 + c];
  }
  __syncthreads();
#pragma unroll
  for (int ii = 0; ii < 16; ii++) {
    int rr = w * 16 + ii;
    unsigned int u = (unsigned int)f2bf(tile[c * 2][rr]) |
                     ((unsigned int)f2bf(tile[c * 2 + 1][rr]) << 16);
    *(unsigned int*)&out[(size_t)(n0 + rr) * ldo + k0 + c * 2] = u;
  }
}

// ---------------------------------------------------------------------------
// 128 x (NF*64) 8-phase bf16 GEMM: C(MxN fp32) = A(MxK) * Bt(NxK)^T
// (exact round-8 version -- verified)
// ---------------------------------------------------------------------------
#define SBAR  do { __builtin_amdgcn_sched_barrier(0); __builtin_amdgcn_s_barrier(); \
                   __builtin_amdgcn_sched_barrier(0); } while (0)
#define LGKM0 do { asm volatile("s_waitcnt lgkmcnt(0)" ::: "memory"); \
                   __builtin_amdgcn_sched_barrier(0); } while (0)
#define VM2   do { asm volatile("s_waitcnt vmcnt(2)" ::: "memory"); } while (0)
#define VM0   do { asm volatile("s_waitcnt vmcnt(0)" ::: "memory"); } while (0)

template <int NF>
__global__ __launch_bounds__(512, 2) void gemm128_bt(const unsigned short* __restrict__ A,
                                                     const unsigned short* __restrict__ Bt,
                                                     float* __restrict__ C,
                                                     int M, int N, int K) {
  constexpr int NHF = NF / 2;             // B frags per qn group per wave
  constexpr int BROWS = 128 + NF * 64;    // rows staged per buffer
  __shared__ __attribute__((aligned(128))) unsigned short smem[2][BROWS * 64];

  const int tid  = threadIdx.x;
  const int lane = tid & 63;
  const int wid  = tid >> 6;      // 0..7
  const int wr   = wid >> 2;      // 0..1  (M half: 64 rows)
  const int wc   = wid & 3;       // 0..3  (N quarter: NF*16 cols)
  const int la   = lane & 15;
  const int lq   = lane >> 4;
  const int sw   = la & 7;        // read-side swizzle key (row&7 == la&7)
  const int m0   = blockIdx.x * 128;
  const int n0   = blockIdx.y * (NF * 64);

  const int sr = lane >> 3;
  const int sl = (lane & 7) ^ sr;

  const unsigned short* gA[2];
  const unsigned short* gB[NHF][2];
#pragma unroll
  for (int is = 0; is < 2; ++is) {
    int r = (wid * 2 + is) * 8 + sr;
    gA[is] = A + (size_t)(m0 + r) * K + sl * 8;
#pragma unroll
    for (int u = 0; u < NHF; ++u)
      gB[u][is] = Bt + (size_t)(n0 + u * 128 + r) * K + sl * 8;
  }

#define G_STG_A(buf, kt) do { \
    async_cp16(gA[0] + (size_t)(kt) * 64, &smem[buf][(wid * 2 + 0) * 512]); \
    async_cp16(gA[1] + (size_t)(kt) * 64, &smem[buf][(wid * 2 + 1) * 512]); \
  } while (0)
#define G_STG_B(buf, u, kt) do { \
    async_cp16(gB[u][0] + (size_t)(kt) * 64, &smem[buf][(128 + (u) * 128) * 64 + (wid * 2 + 0) * 512]); \
    async_cp16(gB[u][1] + (size_t)(kt) * 64, &smem[buf][(128 + (u) * 128) * 64 + (wid * 2 + 1) * 512]); \
  } while (0)

  f32x4  acc[4][NF] = {};
  bf16x8 aR[2][2], b0r[NHF][2], b1r[NHF][2];

#define G_RD_A(buf, qm) do { \
    const unsigned short* rp_ = &smem[buf][0]; \
    _Pragma("unroll") \
    for (int i_ = 0; i_ < 2; ++i_) { \
      int ro_ = (wr * 64 + (qm) * 32 + i_ * 16 + la) * 64; \
      aR[i_][0] = frag_ld(rp_ + ro_ + (((0 + lq) ^ sw) << 3)); \
      aR[i_][1] = frag_ld(rp_ + ro_ + (((4 + lq) ^ sw) << 3)); \
    } \
  } while (0)
#define G_RD_B(buf, qn, breg) do { \
    const unsigned short* rp_ = &smem[buf][128 * 64]; \
    _Pragma("unroll") \
    for (int j_ = 0; j_ < NHF; ++j_) { \
      int ro_ = (wc * (NF * 16) + (qn) * (NF * 8) + j_ * 16 + la) * 64; \
      breg[j_][0] = frag_ld(rp_ + ro_ + (((0 + lq) ^ sw) << 3)); \
      breg[j_][1] = frag_ld(rp_ + ro_ + (((4 + lq) ^ sw) << 3)); \
    } \
  } while (0)
#define G_MMA(qm, qn, breg) do { \
    _Pragma("unroll") \
    for (int i_ = 0; i_ < 2; ++i_) \
      _Pragma("unroll") \
      for (int j_ = 0; j_ < NHF; ++j_) { \
        f32x4 c_ = acc[(qm) * 2 + i_][(qn) * NHF + j_]; \
        c_ = mfma16(aR[i_][0], breg[j_][0], c_); \
        c_ = mfma16(aR[i_][1], breg[j_][1], c_); \
        acc[(qm) * 2 + i_][(qn) * NHF + j_] = c_; \
      } \
  } while (0)

  // prologue: tile0 fully -> buf0; tile1's prev-P8-role slot -> buf1.
  G_STG_A(0, 0);
#pragma unroll
  for (int u = 0; u < NHF; ++u) G_STG_B(0, u, 0);
  if constexpr (NF == 6) G_STG_B(1, 2, 1); else G_STG_A(1, 1);
  VM2;   // tile0's slots landed; the buf1 slot may stay in flight
  SBAR;

  const int NI = K >> 7;   // iterations of 2 K-tiles (K multiple of 128)
  for (int it = 0; it < NI; ++it) {
    const int e = it * 2;
    const bool pf = (it + 1 < NI);
    // ---- P1
    G_RD_A(0, 0);
    G_RD_B(0, 0, b0r);
    if constexpr (NF == 6) G_STG_A(1, e + 1); else G_STG_B(1, 0, e + 1);
    SBAR; LGKM0;
    __builtin_amdgcn_s_setprio(1); G_MMA(0, 0, b0r); __builtin_amdgcn_s_setprio(0);
    SBAR;
    // ---- P2
    G_RD_B(0, 1, b1r);
    if constexpr (NF == 6) G_STG_B(1, 0, e + 1); else G_STG_B(1, 1, e + 1);
    SBAR; LGKM0;
    __builtin_amdgcn_s_setprio(1); G_MMA(0, 1, b1r); __builtin_amdgcn_s_setprio(0);
    SBAR;
    // ---- P3
    G_RD_A(0, 1);
    if constexpr (NF == 6) G_STG_B(1, 1, e + 1);
    SBAR; LGKM0;
    __builtin_amdgcn_s_setprio(1); G_MMA(1, 1, b1r); __builtin_amdgcn_s_setprio(0);
    SBAR;
    // ---- P4
    if (pf) G_STG_A(0, e + 2);
    SBAR; LGKM0;
    __builtin_amdgcn_s_setprio(1); G_MMA(1, 0, b0r); __builtin_amdgcn_s_setprio(0);
    if (pf) { VM2; } else { VM0; }
    SBAR;
    // ---- P5
    G_RD_A(1, 0);
    G_RD_B(1, 0, b0r);
    if (pf) G_STG_B(0, 0, e + 2);
    SBAR; LGKM0;
    __builtin_amdgcn_s_setprio(1); G_MMA(0, 0, b0r); __builtin_amdgcn_s_setprio(0);
    SBAR;
    // ---- P6
    G_RD_B(1, 1, b1r);
    if (pf) G_STG_B(0, 1, e + 2);
    SBAR; LGKM0;
    __builtin_amdgcn_s_setprio(1); G_MMA(0, 1, b1r); __builtin_amdgcn_s_setprio(0);
    SBAR;
    // ---- P7
    G_RD_A(1, 1);
    if constexpr (NF == 6) { if (pf) G_STG_B(0, 2, e + 2); }
    SBAR; LGKM0;
    __builtin_amdgcn_s_setprio(1); G_MMA(1, 1, b1r); __builtin_amdgcn_s_setprio(0);
    SBAR;
    // ---- P8
    if constexpr (NF == 6) { if (pf) G_STG_B(1, 2, e + 3); }
    else                   { if (pf) G_STG_A(1, e + 3); }
    SBAR; LGKM0;
    __builtin_amdgcn_s_setprio(1); G_MMA(1, 0, b0r); __builtin_amdgcn_s_setprio(0);
    VM2;
    SBAR;
  }

  // epilogue: C[row, col], col = frag col + la, row = lq*4 + r within frag
#pragma unroll
  for (int mf = 0; mf < 4; ++mf) {
    int row = m0 + wr * 64 + mf * 16 + lq * 4;
#pragma unroll
    for (int nf = 0; nf < NF; ++nf) {
      int col = n0 + wc * (NF * 16) + nf * 16 + la;
#pragma unroll
      for (int r = 0; r < 4; ++r)
        C[(size_t)(row + r) * N + col] = acc[mf][nf][r];
    }
  }
#undef G_STG_A
#undef G_STG_B
#undef G_RD_A
#undef G_RD_B
#undef G_MMA
}

// ---------------------------------------------------------------------------
// Flash attention v2, swapped-QK^T, fused epilogue, FUSED ROPE.
//
// Change vs round 12 (single subsystem): rope_kernel is gone. Each flash
// block ropes its OWN q rows in the prologue (QKV fp32 -> same y1/y2 math ->
// same f2bf -> aq, bit-identical QK^T operands) and computes kn on the fly in
// the diagonal epilogue (same formulas; e2's fma order interleaves h2 -- fp32
// ulp-level only). Both sites are outside the main loop: transient registers,
// peak VGPR unchanged (r11 lesson). Removes q_b/knew buffers + ~45 MB traffic
// + one launch.
__global__ __launch_bounds__(256, 3) void flash_kernel(const float* __restrict__ QKV,
                                                       const unsigned short* __restrict__ k0b,
                                                       const unsigned short* __restrict__ v0t,
                                                       const float* __restrict__ prev_k,
                                                       const float* __restrict__ prev_v,
                                                       const int* __restrict__ pos_ids,
                                                       unsigned short* __restrict__ attnout) {
  __shared__ unsigned short sK[2][64 * 64];
  __shared__ unsigned short sV[2][64 * 64];
  __shared__ unsigned short sP[4][2][16 * 72];

  const int tid = threadIdx.x;
  const int lane = tid & 63;
  const int wave = tid >> 6;
  const int la = lane & 15;
  const int lq = lane >> 4;
  const int swz = la & 7;

  const int id = blockIdx.x;
  const int bh = (id & 7) * 8 + ((id >> 3) & 7);
  const int qt = 15 - (id >> 6);

  const size_t bhs = (size_t)bh;
  const unsigned short* gK = k0b + bhs * T_ * HD_;
  const unsigned short* gV = v0t + bhs * HD_ * T_;

  const int rb0 = qt * 128 + wave * 32;
  const int ktd = rb0 >> 6;
  const int ktmax = 2 * qt + 1;

  const int bI = bh >> 5;
  const int hI = bh & 31;
  const int kvI = hI >> 2;

  const int lrow = lane >> 3;
  const int lcb = (lane & 7) ^ lrow;

  // issue initial K/V staging first; rope math below hides the DMA latency
  {
    unsigned short* kd = &sK[0][wave * 1024];
    unsigned short* vd = &sV[0][wave * 1024];
    async_cp16(gK + (size_t)(wave * 16 + lrow) * HD_ + lcb * 8, kd);
    async_cp16(gK + (size_t)(wave * 16 + 8 + lrow) * HD_ + lcb * 8, kd + 512);
    async_cp16(gV + (size_t)(wave * 16 + lrow) * T_ + lcb * 8, vd);
    async_cp16(gV + (size_t)(wave * 16 + 8 + lrow) * T_ + lcb * 8, vd + 512);
  }

  // fused RoPE for q: build aq from QKV fp32 (cols hI*64 + i / +32+i)
  bf16x8 aq[2][2];
#pragma unroll
  for (int f = 0; f < 2; f++) {
    const int t = rb0 + f * 16 + la;
    const int pos = pos_ids[bI * T_ + t] + STEPS_;
    const float* qrow = QKV + ((size_t)(bI * T_ + t)) * 3072 + hI * 64;
    u16x8 a0, a1;
#pragma unroll
    for (int j = 0; j < 8; j++) {
      int i = lq * 8 + j;
      float inv = exp2f(-(float)i * (13.287712379549449f / 32.0f));
      float ang = (float)pos * inv;
      float ss, cc;
      sincosf(ang, &ss, &cc);
      float x1 = qrow[i];
      float x2 = qrow[32 + i];
      a0[j] = f2bf((x1 * cc - x2 * ss) * CSC_);
      a1[j] = f2bf((x2 * cc + x1 * ss) * CSC_);
    }
    aq[f][0] = __builtin_bit_cast(bf16x8, a0);
    aq[f][1] = __builtin_bit_cast(bf16x8, a1);
  }

  f32x4 o[2][4] = {};
  float m_f[2] = {-1e30f, -1e30f};
  float l_p[2] = {0.0f, 0.0f};   // per-lane partial row-sum (lq-slice)

  __syncthreads();

  int cur = 0;
  for (int kt = 0; kt <= ktmax; ++kt) {
    if (kt < ktmax) {
      const int nk = (kt + 1) * 64;
      unsigned short* kd = &sK[cur ^ 1][wave * 1024];
      unsigned short* vd = &sV[cur ^ 1][wave * 1024];
      async_cp16(gK + (size_t)(nk + wave * 16 + lrow) * HD_ + lcb * 8, kd);
      async_cp16(gK + (size_t)(nk + wave * 16 + 8 + lrow) * HD_ + lcb * 8, kd + 512);
      async_cp16(gV + (size_t)(wave * 16 + lrow) * T_ + nk + lcb * 8, vd);
      async_cp16(gV + (size_t)(wave * 16 + 8 + lrow) * T_ + nk + lcb * 8, vd + 512);
    }

    if (kt <= ktd) {
      const unsigned short* kb = &sK[cur][0];
      const unsigned short* vb = &sV[cur][0];

      bf16x8 bk0[4], bk1[4];
#pragma unroll
      for (int nb = 0; nb < 4; nb++) {
        const unsigned short* rp = kb + (nb * 16 + la) * 64;
        bk0[nb] = frag_ld(rp + ((lq ^ swz) << 3));
        bk1[nb] = frag_ld(rp + (((lq + 4) ^ swz) << 3));
      }
      // S^T = K * Q^T : lane la = q-row (frag f), key = nb*16 + lq*4 + r
      f32x4 s[2][4];
      __builtin_amdgcn_s_setprio(1);
#pragma unroll
      for (int f = 0; f < 2; f++)
#pragma unroll
        for (int nb = 0; nb < 4; nb++) {
          f32x4 z = {0.f, 0.f, 0.f, 0.f};
          z = mfma16(bk0[nb], aq[f][0], z);
          z = mfma16(bk1[nb], aq[f][1], z);
          s[f][nb] = z;
        }
      __builtin_amdgcn_s_setprio(0);

      // V fragment reads issued early: DS latency hides under softmax VALU
      bf16x8 bv0[4], bv1[4];
#pragma unroll
      for (int jd = 0; jd < 4; jd++) {
        const unsigned short* rp = vb + (jd * 16 + la) * 64;
        bv0[jd] = frag_ld(rp + ((lq ^ swz) << 3));
        bv1[jd] = frag_ld(rp + (((lq + 4) ^ swz) << 3));
      }

      const bool diag = (kt == ktd);
#pragma unroll
      for (int f = 0; f < 2; f++) {
        const int qrow = rb0 + f * 16 + la;
        if (diag) {
#pragma unroll
          for (int nb = 0; nb < 4; nb++)
#pragma unroll
            for (int r = 0; r < 4; r++) {
              int key = kt * 64 + nb * 16 + lq * 4 + r;
              s[f][nb][r] = (key <= qrow) ? s[f][nb][r] : -1e30f;
            }
        }
        // per-lane max over this lane's 16 keys (no cross-lane in common path)
        float t0 = fmaxf(fmaxf(s[f][0][0], s[f][0][1]), fmaxf(s[f][0][2], s[f][0][3]));
        float t1 = fmaxf(fmaxf(s[f][1][0], s[f][1][1]), fmaxf(s[f][1][2], s[f][1][3]));
        float t2 = fmaxf(fmaxf(s[f][2][0], s[f][2][1]), fmaxf(s[f][2][2], s[f][2][3]));
        float t3 = fmaxf(fmaxf(s[f][3][0], s[f][3][1]), fmaxf(s[f][3][2], s[f][3][3]));
        float tm = fmaxf(fmaxf(t0, t1), fmaxf(t2, t3));
        // defer-max (T13): rescale only if some lane's slice-max passed m+8
        const bool resc = __any(tm > m_f[f] + 8.0f);
        if (resc) {
          tm = fmaxf(tm, __shfl_xor(tm, 16));
          tm = fmaxf(tm, __shfl_xor(tm, 32));
          float mn = fmaxf(m_f[f], tm);
          float al = exp2f(m_f[f] - mn);   // row-uniform across lq
          m_f[f] = mn;
          l_p[f] *= al;
          // al lives on lane (la = qrow); O accumulator has qrow = lq*4+r
          float a0 = __shfl(al, lq * 4 + 0);
          float a1 = __shfl(al, lq * 4 + 1);
          float a2 = __shfl(al, lq * 4 + 2);
          float a3 = __shfl(al, lq * 4 + 3);
#pragma unroll
          for (int jd = 0; jd < 4; jd++) {
            o[f][jd][0] *= a0;
            o[f][jd][1] *= a1;
            o[f][jd][2] *= a2;
            o[f][jd][3] *= a3;
          }
        }
        float ls = 0.0f;
#pragma unroll
        for (int nb = 0; nb < 4; nb++)
#pragma unroll
          for (int r = 0; r < 4; r++) {
            float p = exp2f(s[f][nb][r] - m_f[f]);
            s[f][nb][r] = p;
            ls += p;
          }
        l_p[f] += ls;   // per-lane partial; lq-reduction deferred to tail
        // write this f's P into its own sP half (both halves live at once)
        unsigned short* pw = &sP[wave][f][0];
#pragma unroll
        for (int nb = 0; nb < 4; nb++) {
          unsigned int p01 = cvtpk_bf16(s[f][nb][0], s[f][nb][1]);
          unsigned int p23 = cvtpk_bf16(s[f][nb][2], s[f][nb][3]);
          unsigned long long pq = ((unsigned long long)p23 << 32) | (unsigned long long)p01;
          *(unsigned long long*)(pw + la * 72 + nb * 16 + lq * 4) = pq;
        }
      }

      // PV: one LDS round-trip wait covers both f halves
#pragma unroll
      for (int f = 0; f < 2; f++) {
        const unsigned short* pr = &sP[wave][f][0];
        bf16x8 ap0 = frag_ld(&pr[la * 72 + lq * 8]);
        bf16x8 ap1 = frag_ld(&pr[la * 72 + 32 + lq * 8]);
        __builtin_amdgcn_s_setprio(1);
#pragma unroll
        for (int jd = 0; jd < 4; jd++) {
          o[f][jd] = mfma16(ap0, bv0[jd], o[f][jd]);
          o[f][jd] = mfma16(ap1, bv1[jd], o[f][jd]);
        }
        __builtin_amdgcn_s_setprio(0);
      }
    }
    __syncthreads();
    cur ^= 1;
  }

  // finalize l: reduce the per-lane partials over the lq axis (once)
#pragma unroll
  for (int f = 0; f < 2; f++) {
    l_p[f] += __shfl_xor(l_p[f], 16);
    l_p[f] += __shfl_xor(l_p[f], 32);
  }

  // ---- fused epilogue: fold diagonal keys (prev_k[1], rope'd new k), write bf16
  const size_t P1 = (size_t)B_ * NH_ * T_ * HD_;
  const float* k1base = prev_k + P1 + bhs * T_ * HD_;
  const float* v1base = prev_v + P1 + bhs * T_ * HD_;
  const float* vnbase = QKV + (size_t)bI * T_ * 3072 + 2560 + kvI * 64;
  unsigned short* aobase = attnout + (size_t)bI * T_ * (NH_ * HD_) + hI * HD_;

#pragma unroll
  for (int f = 0; f < 2; f++) {
    const int rowA = rb0 + f * 16 + la;   // dot-domain row (la), all lq share
    const float* k1p = k1base + (size_t)rowA * HD_;
    const float* krow = QKV + ((size_t)(bI * T_ + rowA)) * 3072 + 2048 + kvI * 64;
    const int pos = pos_ids[bI * T_ + rowA] + STEPS_;
    float e1 = 0.f, e2 = 0.f;
    // e1: prev_k dot (same layout/order as before)
#pragma unroll
    for (int h2 = 0; h2 < 2; h2++) {
      const int dd = h2 * 32 + lq * 8;
#pragma unroll
      for (int j = 0; j < 8; j++) {
        float qv = (h2 == 0) ? (float)aq[f][0][j] : (float)aq[f][1][j];
        e1 = fmaf(qv, k1p[dd + j], e1);
      }
    }
    // e2: rope'd new k computed on the fly (kn[i] = x1 c - x2 s; kn[32+i] = x2 c + x1 s)
#pragma unroll
    for (int j = 0; j < 8; j++) {
      int i = lq * 8 + j;
      float inv = exp2f(-(float)i * (13.287712379549449f / 32.0f));
      float ang = (float)pos * inv;
      float ss, cc;
      sincosf(ang, &ss, &cc);
      float x1 = krow[i];
      float x2 = krow[32 + i];
      e2 = fmaf((float)aq[f][0][j], x1 * cc - x2 * ss, e2);
      e2 = fmaf((float)aq[f][1][j], x2 * cc + x1 * ss, e2);
    }
    e1 += __shfl_xor(e1, 16); e1 += __shfl_xor(e1, 32);
    e2 += __shfl_xor(e2, 16); e2 += __shfl_xor(e2, 32);
    float mx = fmaxf(m_f[f], fmaxf(e1, e2));
    float w0 = exp2f(m_f[f] - mx);
    float w1 = exp2f(e1 - mx);
    float w2 = exp2f(e2 - mx);
    float inv = 1.0f / (l_p[f] * w0 + w1 + w2);
    float s0 = w0 * inv, s1 = w1 * inv, s2 = w2 * inv;
    // move per-row scalars (on lanes 0..15) to the O domain (row = lq*4+r)
    float a0[4], a1[4], a2[4];
#pragma unroll
    for (int r = 0; r < 4; r++) {
      a0[r] = __shfl(s0, lq * 4 + r);
      a1[r] = __shfl(s1, lq * 4 + r);
      a2[r] = __shfl(s2, lq * 4 + r);
    }
#pragma unroll
    for (int r = 0; r < 4; r++) {
      const int rowO = rb0 + f * 16 + lq * 4 + r;
      const float* v1p = v1base + (size_t)rowO * HD_;
      const float* vnp = vnbase + (size_t)rowO * 3072;
      unsigned short* aop = aobase + (size_t)rowO * (NH_ * HD_);
#pragma unroll
      for (int jd = 0; jd < 4; jd++) {
        int d = jd * 16 + la;
        float out = o[f][jd][r] * a0[r] + v1p[d] * a1[r] + vnp[d] * a2[r];
        aop[d] = f2bf(out);
      }
    }
  }
}

// ---------------------------------------------------------------------------
// Workspace layout (bytes; needs ws_size >= 178,257,920)
#define OFF_QKV   ((size_t)0)
#define OFF_XB    ((size_t)50331648)
#define OFF_WQKVT ((size_t)83886080)
#define OFF_WOT   ((size_t)109051904)
#define OFF_K0B   ((size_t)134217728)
#define OFF_V0T   ((size_t)150994944)

extern "C" void kernel_launch(void* const* d_in, const int* in_sizes, int n_in,
                              void* d_out, int out_size, void* d_ws, size_t ws_size,
                              hipStream_t stream) {
  const float* X = (const float*)d_in[0];
  const int* pos = (const int*)d_in[2];
  const float* prevk = (const float*)d_in[3];
  const float* prevv = (const float*)d_in[4];
  const float* Wq = (const float*)d_in[5];
  const float* Wk = (const float*)d_in[6];
  const float* Wv = (const float*)d_in[7];
  const float* Wo = (const float*)d_in[8];

  char* ws = (char*)d_ws;
  float* QKV = (float*)(ws + OFF_QKV);
  unsigned short* Xb = (unsigned short*)(ws + OFF_XB);
  unsigned short* WqkvT = (unsigned short*)(ws + OFF_WQKVT);
  unsigned short* attnout = (unsigned short*)(ws + OFF_WQKVT);
  unsigned short* WoT = (unsigned short*)(ws + OFF_WOT);
  unsigned short* k0b = (unsigned short*)(ws + OFF_K0B);
  unsigned short* v0t = (unsigned short*)(ws + OFF_V0T);

  // merged preprocessing: converts + all transposes, one dispatch
  preproc<<<27648, 256, 0, stream>>>(X, prevk, prevv, Wq, Wk, Wv, Wo,
                                     Xb, k0b, WqkvT, WoT, v0t);

  // QKV GEMM: M=4096, N=3072, K=4096; BM=128, BN=384 -> grid 32x8 = 256
  gemm128_bt<6><<<dim3(32, 8), 512, 0, stream>>>(Xb, WqkvT, QKV, 4096, 3072, 4096);

  // flash with fused RoPE + fused diagonal-key epilogue -> attnout bf16
  flash_kernel<<<1024, 256, 0, stream>>>(QKV, k0b, v0t, prevk, prevv, pos, attnout);

  // Wo GEMM: M=4096, N=2048, K=2048; BM=128, BN=256 -> grid 32x8 = 256
  gemm128_bt<4><<<dim3(32, 8), 512, 0, stream>>>(attnout, WoT, (float*)d_out, 4096, 2048, 2048);
}

// Round 14
// 466.038 us; speedup vs baseline: 1.0926x; 1.0926x over previous
//
#include <hip/hip_runtime.h>

// Problem constants
#define B_    2
#define T_    2048
#define HID_  2048
#define NH_   32
#define NKV_  8
#define HD_   64
#define STEPS_ 2
#define SCALE_ 0.125f
// SCALE * log2(e): scores kept in exp2 domain throughout (folded into q at RoPE)
#define CSC_  0.18033688011112042f

typedef float   f32x4  __attribute__((ext_vector_type(4)));
typedef __bf16  bf16x8 __attribute__((ext_vector_type(8)));
typedef unsigned short u16x8 __attribute__((ext_vector_type(8)));

__device__ __forceinline__ unsigned short f2bf(float f) {
  unsigned int u = __builtin_bit_cast(unsigned int, f);
  u = (u + 0x7fffu + ((u >> 16) & 1u)) >> 16;
  return (unsigned short)u;
}
__device__ __forceinline__ float bf2f(unsigned short h) {
  unsigned int u = ((unsigned int)h) << 16;
  return __builtin_bit_cast(float, u);
}
__device__ __forceinline__ bf16x8 frag_ld(const unsigned short* p) {
  u16x8 v = *(const u16x8*)p;
  return __builtin_bit_cast(bf16x8, v);
}
__device__ __forceinline__ f32x4 mfma16(bf16x8 a, bf16x8 b, f32x4 c) {
  return __builtin_amdgcn_mfma_f32_16x16x32_bf16(a, b, c, 0, 0, 0);
}
__device__ __forceinline__ void async_cp16(const void* g, void* l) {
  __builtin_amdgcn_global_load_lds(
      (const __attribute__((address_space(1))) void*)g,
      (__attribute__((address_space(3))) void*)l, 16, 0, 0);
}
// HW packed f32->bf16 (RNE), no builtin on gfx950 -> inline asm (guide T12)
__device__ __forceinline__ unsigned int cvtpk_bf16(float lo, float hi) {
  unsigned int r;
  asm("v_cvt_pk_bf16_f32 %0, %1, %2" : "=v"(r) : "v"(lo), "v"(hi));
  return r;
}

// ---------------------------------------------------------------------------
// MERGED preprocessing: one dispatch, block-range switch.
//  [0, 16384)          convert X fp32 -> Xb bf16            (4 f32/thread)
//  [16384, 24576)      convert prev_k[0] -> k0b bf16
//  [24576, 25088)      RoPE cos/sin table: cstab[bt*32+i] = {cos,sin}(ang)
//  [25088, 26624)      transpose Wq/Wk/Wv -> WqkvT (128-wide k-tiles)
//  [26624, 27136)      transpose Wo -> WoT
//  [27136, 28160)      transpose prev_v[0] slabs -> v0t
__global__ __launch_bounds__(256) void preproc(const float* __restrict__ X,
                                               const float* __restrict__ prevk,
                                               const float* __restrict__ prevv,
                                               const float* __restrict__ Wq,
                                               const float* __restrict__ Wk,
                                               const float* __restrict__ Wv,
                                               const float* __restrict__ Wo,
                                               const int* __restrict__ pos_ids,
                                               unsigned short* __restrict__ Xb,
                                               unsigned short* __restrict__ k0b,
                                               unsigned short* __restrict__ WqkvT,
                                               unsigned short* __restrict__ WoT,
                                               unsigned short* __restrict__ v0t,
                                               float2* __restrict__ cstab) {
  __shared__ float tile[128][65];
  const int tid = threadIdx.x;
  int blk = blockIdx.x;

  if (blk < 16384) {                      // convert X (4194304 float4 exactly)
    int idx = blk * 256 + tid;
    float4 v = ((const float4*)X)[idx];
    ushort4 o;
    o.x = f2bf(v.x); o.y = f2bf(v.y); o.z = f2bf(v.z); o.w = f2bf(v.w);
    ((ushort4*)Xb)[idx] = o;
    return;
  }
  blk -= 16384;
  if (blk < 8192) {                       // convert prev_k[0] (2097152 float4)
    int idx = blk * 256 + tid;
    float4 v = ((const float4*)prevk)[idx];
    ushort4 o;
    o.x = f2bf(v.x); o.y = f2bf(v.y); o.z = f2bf(v.z); o.w = f2bf(v.w);
    ((ushort4*)k0b)[idx] = o;
    return;
  }
  blk -= 8192;
  if (blk < 512) {                        // rope table: B*T*32 = 131072 entries
    int idx = blk * 256 + tid;            // bt = idx>>5, i = idx&31
    int i = idx & 31;
    int pos = pos_ids[idx >> 5] + STEPS_;
    float inv = exp2f(-(float)i * (13.287712379549449f / 32.0f));
    float ang = (float)pos * inv;
    float ss, cc;
    sincosf(ang, &ss, &cc);
    cstab[idx] = make_float2(cc, ss);
    return;
  }
  blk -= 512;

  const float* in;
  unsigned short* out;
  int N, ldo, k0, n0;
  if (blk < 1536) {                       // Wq/Wk/Wv -> WqkvT [3072][4096]
    int nt = blk % 48, kt = blk / 48;     // kt 0..31
    k0 = kt * 128;
    ldo = 4096;
    if (nt < 32)      { in = Wq; N = 2048; out = WqkvT;                         n0 = nt * 64; }
    else if (nt < 40) { in = Wk; N = 512;  out = WqkvT + (size_t)2048 * 4096;   n0 = (nt - 32) * 64; }
    else              { in = Wv; N = 512;  out = WqkvT + (size_t)2560 * 4096;   n0 = (nt - 40) * 64; }
  } else if (blk < 2048) {                // Wo (2048x2048) -> WoT
    int q = blk - 1536;
    int nt = q % 32, kt = q / 32;         // kt 0..15
    in = Wo; out = WoT; N = 2048; ldo = 2048;
    k0 = kt * 128; n0 = nt * 64;
  } else {                                // prev_v[0] slabs -> v0t [bh][64][T]
    int q = blk - 2048;
    int st = q % 16, bh = q / 16;         // st 0..15, bh 0..63
    in = prevv + (size_t)bh * T_ * HD_;
    out = v0t + (size_t)bh * HD_ * T_;
    N = 64; ldo = T_;
    k0 = st * 128; n0 = 0;
  }

  const int c = tid & 63, w = tid >> 6;
#pragma unroll
  for (int i = 0; i < 32; i++) {
    int r = w * 32 + i;
    tile[r][c] = in[(size_t)(k0 + r) * N + n0 + c];
  }
  __syncthreads();
#pragma unroll
  for (int ii = 0; ii < 16; ii++) {
    int rr = w * 16 + ii;
    unsigned int u = (unsigned int)f2bf(tile[c * 2][rr]) |
                     ((unsigned int)f2bf(tile[c * 2 + 1][rr]) << 16);
    *(unsigned int*)&out[(size_t)(n0 + rr) * ldo + k0 + c * 2] = u;
  }
}

// ---------------------------------------------------------------------------
// 128 x (NF*64) 8-phase bf16 GEMM: C(MxN fp32) = A(MxK) * Bt(NxK)^T
// (exact round-8 version -- verified)
// ---------------------------------------------------------------------------
#define SBAR  do { __builtin_amdgcn_sched_barrier(0); __builtin_amdgcn_s_barrier(); \
                   __builtin_amdgcn_sched_barrier(0); } while (0)
#define LGKM0 do { asm volatile("s_waitcnt lgkmcnt(0)" ::: "memory"); \
                   __builtin_amdgcn_sched_barrier(0); } while (0)
#define VM2   do { asm volatile("s_waitcnt vmcnt(2)" ::: "memory"); } while (0)
#define VM0   do { asm volatile("s_waitcnt vmcnt(0)" ::: "memory"); } while (0)

template <int NF>
__global__ __launch_bounds__(512, 2) void gemm128_bt(const unsigned short* __restrict__ A,
                                                     const unsigned short* __restrict__ Bt,
                                                     float* __restrict__ C,
                                                     int M, int N, int K) {
  constexpr int NHF = NF / 2;             // B frags per qn group per wave
  constexpr int BROWS = 128 + NF * 64;    // rows staged per buffer
  __shared__ __attribute__((aligned(128))) unsigned short smem[2][BROWS * 64];

  const int tid  = threadIdx.x;
  const int lane = tid & 63;
  const int wid  = tid >> 6;      // 0..7
  const int wr   = wid >> 2;      // 0..1  (M half: 64 rows)
  const int wc   = wid & 3;       // 0..3  (N quarter: NF*16 cols)
  const int la   = lane & 15;
  const int lq   = lane >> 4;
  const int sw   = la & 7;        // read-side swizzle key (row&7 == la&7)
  const int m0   = blockIdx.x * 128;
  const int n0   = blockIdx.y * (NF * 64);

  const int sr = lane >> 3;
  const int sl = (lane & 7) ^ sr;

  const unsigned short* gA[2];
  const unsigned short* gB[NHF][2];
#pragma unroll
  for (int is = 0; is < 2; ++is) {
    int r = (wid * 2 + is) * 8 + sr;
    gA[is] = A + (size_t)(m0 + r) * K + sl * 8;
#pragma unroll
    for (int u = 0; u < NHF; ++u)
      gB[u][is] = Bt + (size_t)(n0 + u * 128 + r) * K + sl * 8;
  }

#define G_STG_A(buf, kt) do { \
    async_cp16(gA[0] + (size_t)(kt) * 64, &smem[buf][(wid * 2 + 0) * 512]); \
    async_cp16(gA[1] + (size_t)(kt) * 64, &smem[buf][(wid * 2 + 1) * 512]); \
  } while (0)
#define G_STG_B(buf, u, kt) do { \
    async_cp16(gB[u][0] + (size_t)(kt) * 64, &smem[buf][(128 + (u) * 128) * 64 + (wid * 2 + 0) * 512]); \
    async_cp16(gB[u][1] + (size_t)(kt) * 64, &smem[buf][(128 + (u) * 128) * 64 + (wid * 2 + 1) * 512]); \
  } while (0)

  f32x4  acc[4][NF] = {};
  bf16x8 aR[2][2], b0r[NHF][2], b1r[NHF][2];

#define G_RD_A(buf, qm) do { \
    const unsigned short* rp_ = &smem[buf][0]; \
    _Pragma("unroll") \
    for (int i_ = 0; i_ < 2; ++i_) { \
      int ro_ = (wr * 64 + (qm) * 32 + i_ * 16 + la) * 64; \
      aR[i_][0] = frag_ld(rp_ + ro_ + (((0 + lq) ^ sw) << 3)); \
      aR[i_][1] = frag_ld(rp_ + ro_ + (((4 + lq) ^ sw) << 3)); \
    } \
  } while (0)
#define G_RD_B(buf, qn, breg) do { \
    const unsigned short* rp_ = &smem[buf][128 * 64]; \
    _Pragma("unroll") \
    for (int j_ = 0; j_ < NHF; ++j_) { \
      int ro_ = (wc * (NF * 16) + (qn) * (NF * 8) + j_ * 16 + la) * 64; \
      breg[j_][0] = frag_ld(rp_ + ro_ + (((0 + lq) ^ sw) << 3)); \
      breg[j_][1] = frag_ld(rp_ + ro_ + (((4 + lq) ^ sw) << 3)); \
    } \
  } while (0)
#define G_MMA(qm, qn, breg) do { \
    _Pragma("unroll") \
    for (int i_ = 0; i_ < 2; ++i_) \
      _Pragma("unroll") \
      for (int j_ = 0; j_ < NHF; ++j_) { \
        f32x4 c_ = acc[(qm) * 2 + i_][(qn) * NHF + j_]; \
        c_ = mfma16(aR[i_][0], breg[j_][0], c_); \
        c_ = mfma16(aR[i_][1], breg[j_][1], c_); \
        acc[(qm) * 2 + i_][(qn) * NHF + j_] = c_; \
      } \
  } while (0)

  // prologue: tile0 fully -> buf0; tile1's prev-P8-role slot -> buf1.
  G_STG_A(0, 0);
#pragma unroll
  for (int u = 0; u < NHF; ++u) G_STG_B(0, u, 0);
  if constexpr (NF == 6) G_STG_B(1, 2, 1); else G_STG_A(1, 1);
  VM2;   // tile0's slots landed; the buf1 slot may stay in flight
  SBAR;

  const int NI = K >> 7;   // iterations of 2 K-tiles (K multiple of 128)
  for (int it = 0; it < NI; ++it) {
    const int e = it * 2;
    const bool pf = (it + 1 < NI);
    // ---- P1
    G_RD_A(0, 0);
    G_RD_B(0, 0, b0r);
    if constexpr (NF == 6) G_STG_A(1, e + 1); else G_STG_B(1, 0, e + 1);
    SBAR; LGKM0;
    __builtin_amdgcn_s_setprio(1); G_MMA(0, 0, b0r); __builtin_amdgcn_s_setprio(0);
    SBAR;
    // ---- P2
    G_RD_B(0, 1, b1r);
    if constexpr (NF == 6) G_STG_B(1, 0, e + 1); else G_STG_B(1, 1, e + 1);
    SBAR; LGKM0;
    __builtin_amdgcn_s_setprio(1); G_MMA(0, 1, b1r); __builtin_amdgcn_s_setprio(0);
    SBAR;
    // ---- P3
    G_RD_A(0, 1);
    if constexpr (NF == 6) G_STG_B(1, 1, e + 1);
    SBAR; LGKM0;
    __builtin_amdgcn_s_setprio(1); G_MMA(1, 1, b1r); __builtin_amdgcn_s_setprio(0);
    SBAR;
    // ---- P4
    if (pf) G_STG_A(0, e + 2);
    SBAR; LGKM0;
    __builtin_amdgcn_s_setprio(1); G_MMA(1, 0, b0r); __builtin_amdgcn_s_setprio(0);
    if (pf) { VM2; } else { VM0; }
    SBAR;
    // ---- P5
    G_RD_A(1, 0);
    G_RD_B(1, 0, b0r);
    if (pf) G_STG_B(0, 0, e + 2);
    SBAR; LGKM0;
    __builtin_amdgcn_s_setprio(1); G_MMA(0, 0, b0r); __builtin_amdgcn_s_setprio(0);
    SBAR;
    // ---- P6
    G_RD_B(1, 1, b1r);
    if (pf) G_STG_B(0, 1, e + 2);
    SBAR; LGKM0;
    __builtin_amdgcn_s_setprio(1); G_MMA(0, 1, b1r); __builtin_amdgcn_s_setprio(0);
    SBAR;
    // ---- P7
    G_RD_A(1, 1);
    if constexpr (NF == 6) { if (pf) G_STG_B(0, 2, e + 2); }
    SBAR; LGKM0;
    __builtin_amdgcn_s_setprio(1); G_MMA(1, 1, b1r); __builtin_amdgcn_s_setprio(0);
    SBAR;
    // ---- P8
    if constexpr (NF == 6) { if (pf) G_STG_B(1, 2, e + 3); }
    else                   { if (pf) G_STG_A(1, e + 3); }
    SBAR; LGKM0;
    __builtin_amdgcn_s_setprio(1); G_MMA(1, 0, b0r); __builtin_amdgcn_s_setprio(0);
    VM2;
    SBAR;
  }

  // epilogue: C[row, col], col = frag col + la, row = lq*4 + r within frag
#pragma unroll
  for (int mf = 0; mf < 4; ++mf) {
    int row = m0 + wr * 64 + mf * 16 + lq * 4;
#pragma unroll
    for (int nf = 0; nf < NF; ++nf) {
      int col = n0 + wc * (NF * 16) + nf * 16 + la;
#pragma unroll
      for (int r = 0; r < 4; ++r)
        C[(size_t)(row + r) * N + col] = acc[mf][nf][r];
    }
  }
#undef G_STG_A
#undef G_STG_B
#undef G_RD_A
#undef G_RD_B
#undef G_MMA
}

// ---------------------------------------------------------------------------
// Flash attention v2, swapped-QK^T, fused epilogue, fused RoPE via TABLE.
//
// Change vs round 13 (single, isolated): all sincosf/exp2f trig in flash is
// replaced by loads from the precomputed cstab [B*T][32] float2 (cos,sin) --
// 1 MB, L2-resident, written by preproc with the identical sincosf values ->
// bit-identical q/kn math. Round-13's on-device trig cost 48 sincosf/thread
// and ~40 MB of scratch writes (WRITE_SIZE 56 MB); table loads cost 8
// contiguous float2 per lane per site.
__global__ __launch_bounds__(256, 3) void flash_kernel(const float* __restrict__ QKV,
                                                       const unsigned short* __restrict__ k0b,
                                                       const unsigned short* __restrict__ v0t,
                                                       const float* __restrict__ prev_k,
                                                       const float* __restrict__ prev_v,
                                                       const float2* __restrict__ cstab,
                                                       unsigned short* __restrict__ attnout) {
  __shared__ unsigned short sK[2][64 * 64];
  __shared__ unsigned short sV[2][64 * 64];
  __shared__ unsigned short sP[4][2][16 * 72];

  const int tid = threadIdx.x;
  const int lane = tid & 63;
  const int wave = tid >> 6;
  const int la = lane & 15;
  const int lq = lane >> 4;
  const int swz = la & 7;

  const int id = blockIdx.x;
  const int bh = (id & 7) * 8 + ((id >> 3) & 7);
  const int qt = 15 - (id >> 6);

  const size_t bhs = (size_t)bh;
  const unsigned short* gK = k0b + bhs * T_ * HD_;
  const unsigned short* gV = v0t + bhs * HD_ * T_;

  const int rb0 = qt * 128 + wave * 32;
  const int ktd = rb0 >> 6;
  const int ktmax = 2 * qt + 1;

  const int bI = bh >> 5;
  const int hI = bh & 31;
  const int kvI = hI >> 2;

  const int lrow = lane >> 3;
  const int lcb = (lane & 7) ^ lrow;

  // issue initial K/V staging first; rope math below hides the DMA latency
  {
    unsigned short* kd = &sK[0][wave * 1024];
    unsigned short* vd = &sV[0][wave * 1024];
    async_cp16(gK + (size_t)(wave * 16 + lrow) * HD_ + lcb * 8, kd);
    async_cp16(gK + (size_t)(wave * 16 + 8 + lrow) * HD_ + lcb * 8, kd + 512);
    async_cp16(gV + (size_t)(wave * 16 + lrow) * T_ + lcb * 8, vd);
    async_cp16(gV + (size_t)(wave * 16 + 8 + lrow) * T_ + lcb * 8, vd + 512);
  }

  // fused RoPE for q: table cos/sin, QKV fp32 -> aq (bit-identical to rope_kernel)
  bf16x8 aq[2][2];
#pragma unroll
  for (int f = 0; f < 2; f++) {
    const int t = rb0 + f * 16 + la;
    const float* qrow = QKV + ((size_t)(bI * T_ + t)) * 3072 + hI * 64;
    const float2* ct = cstab + (size_t)(bI * T_ + t) * 32 + lq * 8;
    u16x8 a0, a1;
#pragma unroll
    for (int j = 0; j < 8; j++) {
      int i = lq * 8 + j;
      float2 cs = ct[j];
      float x1 = qrow[i];
      float x2 = qrow[32 + i];
      a0[j] = f2bf((x1 * cs.x - x2 * cs.y) * CSC_);
      a1[j] = f2bf((x2 * cs.x + x1 * cs.y) * CSC_);
    }
    aq[f][0] = __builtin_bit_cast(bf16x8, a0);
    aq[f][1] = __builtin_bit_cast(bf16x8, a1);
  }

  f32x4 o[2][4] = {};
  float m_f[2] = {-1e30f, -1e30f};
  float l_p[2] = {0.0f, 0.0f};   // per-lane partial row-sum (lq-slice)

  __syncthreads();

  int cur = 0;
  for (int kt = 0; kt <= ktmax; ++kt) {
    if (kt < ktmax) {
      const int nk = (kt + 1) * 64;
      unsigned short* kd = &sK[cur ^ 1][wave * 1024];
      unsigned short* vd = &sV[cur ^ 1][wave * 1024];
      async_cp16(gK + (size_t)(nk + wave * 16 + lrow) * HD_ + lcb * 8, kd);
      async_cp16(gK + (size_t)(nk + wave * 16 + 8 + lrow) * HD_ + lcb * 8, kd + 512);
      async_cp16(gV + (size_t)(wave * 16 + lrow) * T_ + nk + lcb * 8, vd);
      async_cp16(gV + (size_t)(wave * 16 + 8 + lrow) * T_ + nk + lcb * 8, vd + 512);
    }

    if (kt <= ktd) {
      const unsigned short* kb = &sK[cur][0];
      const unsigned short* vb = &sV[cur][0];

      bf16x8 bk0[4], bk1[4];
#pragma unroll
      for (int nb = 0; nb < 4; nb++) {
        const unsigned short* rp = kb + (nb * 16 + la) * 64;
        bk0[nb] = frag_ld(rp + ((lq ^ swz) << 3));
        bk1[nb] = frag_ld(rp + (((lq + 4) ^ swz) << 3));
      }
      // S^T = K * Q^T : lane la = q-row (frag f), key = nb*16 + lq*4 + r
      f32x4 s[2][4];
      __builtin_amdgcn_s_setprio(1);
#pragma unroll
      for (int f = 0; f < 2; f++)
#pragma unroll
        for (int nb = 0; nb < 4; nb++) {
          f32x4 z = {0.f, 0.f, 0.f, 0.f};
          z = mfma16(bk0[nb], aq[f][0], z);
          z = mfma16(bk1[nb], aq[f][1], z);
          s[f][nb] = z;
        }
      __builtin_amdgcn_s_setprio(0);

      // V fragment reads issued early: DS latency hides under softmax VALU
      bf16x8 bv0[4], bv1[4];
#pragma unroll
      for (int jd = 0; jd < 4; jd++) {
        const unsigned short* rp = vb + (jd * 16 + la) * 64;
        bv0[jd] = frag_ld(rp + ((lq ^ swz) << 3));
        bv1[jd] = frag_ld(rp + (((lq + 4) ^ swz) << 3));
      }

      const bool diag = (kt == ktd);
#pragma unroll
      for (int f = 0; f < 2; f++) {
        const int qrow = rb0 + f * 16 + la;
        if (diag) {
#pragma unroll
          for (int nb = 0; nb < 4; nb++)
#pragma unroll
            for (int r = 0; r < 4; r++) {
              int key = kt * 64 + nb * 16 + lq * 4 + r;
              s[f][nb][r] = (key <= qrow) ? s[f][nb][r] : -1e30f;
            }
        }
        // per-lane max over this lane's 16 keys (no cross-lane in common path)
        float t0 = fmaxf(fmaxf(s[f][0][0], s[f][0][1]), fmaxf(s[f][0][2], s[f][0][3]));
        float t1 = fmaxf(fmaxf(s[f][1][0], s[f][1][1]), fmaxf(s[f][1][2], s[f][1][3]));
        float t2 = fmaxf(fmaxf(s[f][2][0], s[f][2][1]), fmaxf(s[f][2][2], s[f][2][3]));
        float t3 = fmaxf(fmaxf(s[f][3][0], s[f][3][1]), fmaxf(s[f][3][2], s[f][3][3]));
        float tm = fmaxf(fmaxf(t0, t1), fmaxf(t2, t3));
        // defer-max (T13): rescale only if some lane's slice-max passed m+8
        const bool resc = __any(tm > m_f[f] + 8.0f);
        if (resc) {
          tm = fmaxf(tm, __shfl_xor(tm, 16));
          tm = fmaxf(tm, __shfl_xor(tm, 32));
          float mn = fmaxf(m_f[f], tm);
          float al = exp2f(m_f[f] - mn);   // row-uniform across lq
          m_f[f] = mn;
          l_p[f] *= al;
          // al lives on lane (la = qrow); O accumulator has qrow = lq*4+r
          float a0 = __shfl(al, lq * 4 + 0);
          float a1 = __shfl(al, lq * 4 + 1);
          float a2 = __shfl(al, lq * 4 + 2);
          float a3 = __shfl(al, lq * 4 + 3);
#pragma unroll
          for (int jd = 0; jd < 4; jd++) {
            o[f][jd][0] *= a0;
            o[f][jd][1] *= a1;
            o[f][jd][2] *= a2;
            o[f][jd][3] *= a3;
          }
        }
        float ls = 0.0f;
#pragma unroll
        for (int nb = 0; nb < 4; nb++)
#pragma unroll
          for (int r = 0; r < 4; r++) {
            float p = exp2f(s[f][nb][r] - m_f[f]);
            s[f][nb][r] = p;
            ls += p;
          }
        l_p[f] += ls;   // per-lane partial; lq-reduction deferred to tail
        // write this f's P into its own sP half (both halves live at once)
        unsigned short* pw = &sP[wave][f][0];
#pragma unroll
        for (int nb = 0; nb < 4; nb++) {
          unsigned int p01 = cvtpk_bf16(s[f][nb][0], s[f][nb][1]);
          unsigned int p23 = cvtpk_bf16(s[f][nb][2], s[f][nb][3]);
          unsigned long long pq = ((unsigned long long)p23 << 32) | (unsigned long long)p01;
          *(unsigned long long*)(pw + la * 72 + nb * 16 + lq * 4) = pq;
        }
      }

      // PV: one LDS round-trip wait covers both f halves
#pragma unroll
      for (int f = 0; f < 2; f++) {
        const unsigned short* pr = &sP[wave][f][0];
        bf16x8 ap0 = frag_ld(&pr[la * 72 + lq * 8]);
        bf16x8 ap1 = frag_ld(&pr[la * 72 + 32 + lq * 8]);
        __builtin_amdgcn_s_setprio(1);
#pragma unroll
        for (int jd = 0; jd < 4; jd++) {
          o[f][jd] = mfma16(ap0, bv0[jd], o[f][jd]);
          o[f][jd] = mfma16(ap1, bv1[jd], o[f][jd]);
        }
        __builtin_amdgcn_s_setprio(0);
      }
    }
    __syncthreads();
    cur ^= 1;
  }

  // finalize l: reduce the per-lane partials over the lq axis (once)
#pragma unroll
  for (int f = 0; f < 2; f++) {
    l_p[f] += __shfl_xor(l_p[f], 16);
    l_p[f] += __shfl_xor(l_p[f], 32);
  }

  // ---- fused epilogue: fold diagonal keys (prev_k[1], rope'd new k), write bf16
  const size_t P1 = (size_t)B_ * NH_ * T_ * HD_;
  const float* k1base = prev_k + P1 + bhs * T_ * HD_;
  const float* v1base = prev_v + P1 + bhs * T_ * HD_;
  const float* vnbase = QKV + (size_t)bI * T_ * 3072 + 2560 + kvI * 64;
  unsigned short* aobase = attnout + (size_t)bI * T_ * (NH_ * HD_) + hI * HD_;

#pragma unroll
  for (int f = 0; f < 2; f++) {
    const int rowA = rb0 + f * 16 + la;   // dot-domain row (la), all lq share
    const float* k1p = k1base + (size_t)rowA * HD_;
    const float* krow = QKV + ((size_t)(bI * T_ + rowA)) * 3072 + 2048 + kvI * 64;
    const float2* ct = cstab + (size_t)(bI * T_ + rowA) * 32 + lq * 8;
    float e1 = 0.f, e2 = 0.f;
    // e1: prev_k dot (same layout/order as before)
#pragma unroll
    for (int h2 = 0; h2 < 2; h2++) {
      const int dd = h2 * 32 + lq * 8;
#pragma unroll
      for (int j = 0; j < 8; j++) {
        float qv = (h2 == 0) ? (float)aq[f][0][j] : (float)aq[f][1][j];
        e1 = fmaf(qv, k1p[dd + j], e1);
      }
    }
    // e2: rope'd new k from table (kn[i] = x1 c - x2 s; kn[32+i] = x2 c + x1 s)
#pragma unroll
    for (int j = 0; j < 8; j++) {
      int i = lq * 8 + j;
      float2 cs = ct[j];
      float x1 = krow[i];
      float x2 = krow[32 + i];
      e2 = fmaf((float)aq[f][0][j], x1 * cs.x - x2 * cs.y, e2);
      e2 = fmaf((float)aq[f][1][j], x2 * cs.x + x1 * cs.y, e2);
    }
    e1 += __shfl_xor(e1, 16); e1 += __shfl_xor(e1, 32);
    e2 += __shfl_xor(e2, 16); e2 += __shfl_xor(e2, 32);
    float mx = fmaxf(m_f[f], fmaxf(e1, e2));
    float w0 = exp2f(m_f[f] - mx);
    float w1 = exp2f(e1 - mx);
    float w2 = exp2f(e2 - mx);
    float inv = 1.0f / (l_p[f] * w0 + w1 + w2);
    float s0 = w0 * inv, s1 = w1 * inv, s2 = w2 * inv;
    // move per-row scalars (on lanes 0..15) to the O domain (row = lq*4+r)
    float a0[4], a1[4], a2[4];
#pragma unroll
    for (int r = 0; r < 4; r++) {
      a0[r] = __shfl(s0, lq * 4 + r);
      a1[r] = __shfl(s1, lq * 4 + r);
      a2[r] = __shfl(s2, lq * 4 + r);
    }
#pragma unroll
    for (int r = 0; r < 4; r++) {
      const int rowO = rb0 + f * 16 + lq * 4 + r;
      const float* v1p = v1base + (size_t)rowO * HD_;
      const float* vnp = vnbase + (size_t)rowO * 3072;
      unsigned short* aop = aobase + (size_t)rowO * (NH_ * HD_);
#pragma unroll
      for (int jd = 0; jd < 4; jd++) {
        int d = jd * 16 + la;
        float out = o[f][jd][r] * a0[r] + v1p[d] * a1[r] + vnp[d] * a2[r];
        aop[d] = f2bf(out);
      }
    }
  }
}

// ---------------------------------------------------------------------------
// Workspace layout (bytes; needs ws_size >= 178,257,920)
#define OFF_QKV   ((size_t)0)
#define OFF_XB    ((size_t)50331648)
#define OFF_WQKVT ((size_t)83886080)
#define OFF_WOT   ((size_t)109051904)
#define OFF_K0B   ((size_t)134217728)
#define OFF_V0T   ((size_t)150994944)
#define OFF_CS    ((size_t)167772160)

extern "C" void kernel_launch(void* const* d_in, const int* in_sizes, int n_in,
                              void* d_out, int out_size, void* d_ws, size_t ws_size,
                              hipStream_t stream) {
  const float* X = (const float*)d_in[0];
  const int* pos = (const int*)d_in[2];
  const float* prevk = (const float*)d_in[3];
  const float* prevv = (const float*)d_in[4];
  const float* Wq = (const float*)d_in[5];
  const float* Wk = (const float*)d_in[6];
  const float* Wv = (const float*)d_in[7];
  const float* Wo = (const float*)d_in[8];

  char* ws = (char*)d_ws;
  float* QKV = (float*)(ws + OFF_QKV);
  unsigned short* Xb = (unsigned short*)(ws + OFF_XB);
  unsigned short* WqkvT = (unsigned short*)(ws + OFF_WQKVT);
  unsigned short* attnout = (unsigned short*)(ws + OFF_WQKVT);
  unsigned short* WoT = (unsigned short*)(ws + OFF_WOT);
  unsigned short* k0b = (unsigned short*)(ws + OFF_K0B);
  unsigned short* v0t = (unsigned short*)(ws + OFF_V0T);
  float2* cstab = (float2*)(ws + OFF_CS);

  // merged preprocessing: converts + rope table + all transposes, one dispatch
  preproc<<<28160, 256, 0, stream>>>(X, prevk, prevv, Wq, Wk, Wv, Wo, pos,
                                     Xb, k0b, WqkvT, WoT, v0t, cstab);

  // QKV GEMM: M=4096, N=3072, K=4096; BM=128, BN=384 -> grid 32x8 = 256
  gemm128_bt<6><<<dim3(32, 8), 512, 0, stream>>>(Xb, WqkvT, QKV, 4096, 3072, 4096);

  // flash with fused table-RoPE + fused diagonal-key epilogue -> attnout bf16
  flash_kernel<<<1024, 256, 0, stream>>>(QKV, k0b, v0t, prevk, prevv, cstab, attnout);

  // Wo GEMM: M=4096, N=2048, K=2048; BM=128, BN=256 -> grid 32x8 = 256
  gemm128_bt<4><<<dim3(32, 8), 512, 0, stream>>>(attnout, WoT, (float*)d_out, 4096, 2048, 2048);
}